// Round 1
// baseline (198.258 us; speedup 1.0000x reference)
//
#include <hip/hip_runtime.h>

#define NF   16
#define C    8
#define NB   4
#define NPIX (512*512)

// ws float layout:
//   [0,512)     sums[b][c*16+f]
//   [512,544)   counts[b*8+c]
//   [544,1056)  means[b][f*8+c]   (transposed for conflict-free LDS gather)
//   [1056,1060) invsum[b]
#define WS_CNT   512
#define WS_MEAN  544
#define WS_INV   1056
#define WS_TOTAL 1060

__global__ void init_kernel(float* __restrict__ ws, float* __restrict__ out) {
    int t = blockIdx.x * blockDim.x + threadIdx.x;
    if (t < WS_TOTAL) ws[t] = 0.0f;
    if (t == 0) out[0] = 0.0f;
}

__global__ __launch_bounds__(256) void sums_kernel(const float* __restrict__ pred,
                                                   const int* __restrict__ tgt,
                                                   float* __restrict__ ws) {
    __shared__ float s_acc[C * NF];
    __shared__ float s_cnt[C];
    const int tid = threadIdx.x;
    const int b   = blockIdx.y;
    if (tid < C * NF) s_acc[tid] = 0.0f;
    if (tid < C)      s_cnt[tid] = 0.0f;
    __syncthreads();

    const float* predb = pred + (size_t)b * NF * NPIX;
    const int*   tgtb  = tgt  + (size_t)b * NPIX;
    const int stride = gridDim.x * blockDim.x * 4;
    for (int base = (blockIdx.x * blockDim.x + tid) * 4; base < NPIX; base += stride) {
        int4 lab = *(const int4*)(tgtb + base);
        atomicAdd(&s_cnt[lab.x], 1.0f);
        atomicAdd(&s_cnt[lab.y], 1.0f);
        atomicAdd(&s_cnt[lab.z], 1.0f);
        atomicAdd(&s_cnt[lab.w], 1.0f);
#pragma unroll
        for (int f = 0; f < NF; ++f) {
            float4 p = *(const float4*)(predb + f * NPIX + base);
            atomicAdd(&s_acc[lab.x * NF + f], p.x);
            atomicAdd(&s_acc[lab.y * NF + f], p.y);
            atomicAdd(&s_acc[lab.z * NF + f], p.z);
            atomicAdd(&s_acc[lab.w * NF + f], p.w);
        }
    }
    __syncthreads();
    float* gsum = ws + b * (C * NF);
    float* gcnt = ws + WS_CNT + b * C;
    if (tid < C * NF) atomicAdd(&gsum[tid], s_acc[tid]);
    if (tid < C)      atomicAdd(&gcnt[tid], s_cnt[tid]);
}

__global__ void means_kernel(float* __restrict__ ws) {
    int t = threadIdx.x;               // 512 threads: b=t/128, c=(t/16)%8, f=t%16
    int b = t >> 7;
    int r = t & 127;
    int c = r >> 4;
    int f = r & 15;
    float cnt = ws[WS_CNT + b * C + c];
    ws[WS_MEAN + b * 128 + f * C + c] = ws[b * 128 + c * NF + f] / cnt;
    if (f == 0) atomicAdd(&ws[WS_INV + b], 1.0f / cnt);
}

__global__ __launch_bounds__(256) void dist_kernel(const float* __restrict__ pred,
                                                   const int* __restrict__ tgt,
                                                   const float* __restrict__ ws,
                                                   float* __restrict__ out) {
    __shared__ float s_means[C * NF];
    __shared__ float s_red[4];
    const int tid = threadIdx.x;
    const int b   = blockIdx.y;
    if (tid < C * NF) s_means[tid] = ws[WS_MEAN + b * 128 + tid];
    const float invs = ws[WS_INV + b];
    __syncthreads();

    const float* predb = pred + (size_t)b * NF * NPIX;
    const int*   tgtb  = tgt  + (size_t)b * NPIX;
    float acc = 0.0f;
    const int stride = gridDim.x * blockDim.x * 4;
    for (int base = (blockIdx.x * blockDim.x + tid) * 4; base < NPIX; base += stride) {
        int4 lab = *(const int4*)(tgtb + base);
        float s0 = 0.f, s1 = 0.f, s2 = 0.f, s3 = 0.f;
#pragma unroll
        for (int f = 0; f < NF; ++f) {
            float4 p = *(const float4*)(predb + f * NPIX + base);
            float d0 = s_means[f * C + lab.x] - p.x;
            float d1 = s_means[f * C + lab.y] - p.y;
            float d2 = s_means[f * C + lab.z] - p.z;
            float d3 = s_means[f * C + lab.w] - p.w;
            s0 += d0 * d0; s1 += d1 * d1; s2 += d2 * d2; s3 += d3 * d3;
        }
        float t0 = fminf(fmaxf(sqrtf(s0) - 0.5f, 0.0f), 100000.0f);
        float t1 = fminf(fmaxf(sqrtf(s1) - 0.5f, 0.0f), 100000.0f);
        float t2 = fminf(fmaxf(sqrtf(s2) - 0.5f, 0.0f), 100000.0f);
        float t3 = fminf(fmaxf(sqrtf(s3) - 0.5f, 0.0f), 100000.0f);
        acc += t0 * t0 + t1 * t1 + t2 * t2 + t3 * t3;
    }
    // wave (64-lane) shuffle reduce, then cross-wave via LDS
#pragma unroll
    for (int off = 32; off > 0; off >>= 1) acc += __shfl_down(acc, off);
    const int lane = tid & 63, wave = tid >> 6;
    if (lane == 0) s_red[wave] = acc;
    __syncthreads();
    if (tid == 0) {
        float tot = s_red[0] + s_red[1] + s_red[2] + s_red[3];
        atomicAdd(out, tot * invs * 0.125f);
    }
}

extern "C" void kernel_launch(void* const* d_in, const int* in_sizes, int n_in,
                              void* d_out, int out_size, void* d_ws, size_t ws_size,
                              hipStream_t stream) {
    const float* pred = (const float*)d_in[0];
    const int*   tgt  = (const int*)d_in[1];
    float* out = (float*)d_out;
    float* ws  = (float*)d_ws;

    init_kernel<<<dim3((WS_TOTAL + 255) / 256), dim3(256), 0, stream>>>(ws, out);
    sums_kernel<<<dim3(128, NB), dim3(256), 0, stream>>>(pred, tgt, ws);
    means_kernel<<<dim3(1), dim3(512), 0, stream>>>(ws);
    dist_kernel<<<dim3(256, NB), dim3(256), 0, stream>>>(pred, tgt, ws, out);
}

// Round 2
// 169.545 us; speedup vs baseline: 1.1694x; 1.1694x over previous
//
#include <hip/hip_runtime.h>

#define NF   16
#define C    8
#define NB   4
#define NPIX (512*512)

// ws float layout:
//   [0,512)     sums[b][c*16+f]
//   [512,544)   counts[b*8+c]
//   [544,1056)  means[b][f*8+c]   (transposed for conflict-free LDS gather)
//   [1056,1060) invsum[b]
#define WS_CNT   512
#define WS_MEAN  544
#define WS_INV   1056
#define WS_TOTAL 1060

__global__ void init_kernel(float* __restrict__ ws, float* __restrict__ out) {
    int t = blockIdx.x * blockDim.x + threadIdx.x;
    if (t < WS_TOTAL) ws[t] = 0.0f;
    if (t == 0) out[0] = 0.0f;
}

// Register-accumulation sums: wave w owns features 4w..4w+3 (no LDS atomics).
// Each lane: acc[4][8] masked-FMA accumulate; wave 0 also counts pixels/instance.
// Tail: 64-lane shuffle butterfly, lane 0 commits 32 (+8) global atomics.
__global__ __launch_bounds__(256) void sums_kernel(const float* __restrict__ pred,
                                                   const int* __restrict__ tgt,
                                                   float* __restrict__ ws) {
    const int tid  = threadIdx.x;
    const int lane = tid & 63;
    const int wave = tid >> 6;          // 0..3
    const int b    = blockIdx.y;
    const int f0   = wave * 4;          // this wave's features: f0..f0+3

    float acc[4][8];
#pragma unroll
    for (int i = 0; i < 4; ++i)
#pragma unroll
        for (int c = 0; c < 8; ++c) acc[i][c] = 0.0f;
    float cnt[8];
#pragma unroll
    for (int c = 0; c < 8; ++c) cnt[c] = 0.0f;

    const float* predb = pred + (size_t)b * NF * NPIX;
    const int*   tgtb  = tgt  + (size_t)b * NPIX;

    const int chunk = NPIX / gridDim.x;           // pixels per block
    const int start = blockIdx.x * chunk;
    for (int base = start + lane * 4; base < start + chunk; base += 64 * 4) {
        int4 lab = *(const int4*)(tgtb + base);
        float m0[8], m1[8], m2[8], m3[8];
#pragma unroll
        for (int c = 0; c < 8; ++c) {
            m0[c] = (lab.x == c) ? 1.0f : 0.0f;
            m1[c] = (lab.y == c) ? 1.0f : 0.0f;
            m2[c] = (lab.z == c) ? 1.0f : 0.0f;
            m3[c] = (lab.w == c) ? 1.0f : 0.0f;
        }
        if (wave == 0) {
#pragma unroll
            for (int c = 0; c < 8; ++c)
                cnt[c] += m0[c] + m1[c] + m2[c] + m3[c];
        }
#pragma unroll
        for (int fi = 0; fi < 4; ++fi) {
            float4 p = *(const float4*)(predb + (f0 + fi) * NPIX + base);
#pragma unroll
            for (int c = 0; c < 8; ++c)
                acc[fi][c] += m0[c] * p.x + m1[c] * p.y + m2[c] * p.z + m3[c] * p.w;
        }
    }

    // within-wave butterfly reduce (features are wave-exclusive, so no cross-wave step)
#pragma unroll
    for (int off = 32; off > 0; off >>= 1) {
#pragma unroll
        for (int fi = 0; fi < 4; ++fi)
#pragma unroll
            for (int c = 0; c < 8; ++c)
                acc[fi][c] += __shfl_down(acc[fi][c], off);
    }
    if (wave == 0) {
#pragma unroll
        for (int off = 32; off > 0; off >>= 1)
#pragma unroll
            for (int c = 0; c < 8; ++c)
                cnt[c] += __shfl_down(cnt[c], off);
    }

    if (lane == 0) {
        float* gsum = ws + b * (C * NF);
#pragma unroll
        for (int fi = 0; fi < 4; ++fi)
#pragma unroll
            for (int c = 0; c < 8; ++c)
                atomicAdd(&gsum[c * NF + (f0 + fi)], acc[fi][c]);
        if (wave == 0) {
            float* gcnt = ws + WS_CNT + b * C;
#pragma unroll
            for (int c = 0; c < 8; ++c)
                atomicAdd(&gcnt[c], cnt[c]);
        }
    }
}

__global__ void means_kernel(float* __restrict__ ws) {
    int t = threadIdx.x;               // 512 threads: b=t/128, c=(t/16)%8, f=t%16
    int b = t >> 7;
    int r = t & 127;
    int c = r >> 4;
    int f = r & 15;
    float cnt = ws[WS_CNT + b * C + c];
    ws[WS_MEAN + b * 128 + f * C + c] = ws[b * 128 + c * NF + f] / cnt;
    if (f == 0) atomicAdd(&ws[WS_INV + b], 1.0f / cnt);
}

__global__ __launch_bounds__(256) void dist_kernel(const float* __restrict__ pred,
                                                   const int* __restrict__ tgt,
                                                   const float* __restrict__ ws,
                                                   float* __restrict__ out) {
    __shared__ float s_means[C * NF];
    __shared__ float s_red[4];
    const int tid = threadIdx.x;
    const int b   = blockIdx.y;
    if (tid < C * NF) s_means[tid] = ws[WS_MEAN + b * 128 + tid];
    const float invs = ws[WS_INV + b];
    __syncthreads();

    const float* predb = pred + (size_t)b * NF * NPIX;
    const int*   tgtb  = tgt  + (size_t)b * NPIX;
    float acc = 0.0f;
    const int stride = gridDim.x * blockDim.x * 4;
    for (int base = (blockIdx.x * blockDim.x + tid) * 4; base < NPIX; base += stride) {
        int4 lab = *(const int4*)(tgtb + base);
        float s0 = 0.f, s1 = 0.f, s2 = 0.f, s3 = 0.f;
#pragma unroll
        for (int f = 0; f < NF; ++f) {
            float4 p = *(const float4*)(predb + f * NPIX + base);
            float d0 = s_means[f * C + lab.x] - p.x;
            float d1 = s_means[f * C + lab.y] - p.y;
            float d2 = s_means[f * C + lab.z] - p.z;
            float d3 = s_means[f * C + lab.w] - p.w;
            s0 += d0 * d0; s1 += d1 * d1; s2 += d2 * d2; s3 += d3 * d3;
        }
        float t0 = fminf(fmaxf(sqrtf(s0) - 0.5f, 0.0f), 100000.0f);
        float t1 = fminf(fmaxf(sqrtf(s1) - 0.5f, 0.0f), 100000.0f);
        float t2 = fminf(fmaxf(sqrtf(s2) - 0.5f, 0.0f), 100000.0f);
        float t3 = fminf(fmaxf(sqrtf(s3) - 0.5f, 0.0f), 100000.0f);
        acc += t0 * t0 + t1 * t1 + t2 * t2 + t3 * t3;
    }
#pragma unroll
    for (int off = 32; off > 0; off >>= 1) acc += __shfl_down(acc, off);
    const int lane = tid & 63, wave = tid >> 6;
    if (lane == 0) s_red[wave] = acc;
    __syncthreads();
    if (tid == 0) {
        float tot = s_red[0] + s_red[1] + s_red[2] + s_red[3];
        atomicAdd(out, tot * invs * 0.125f);
    }
}

extern "C" void kernel_launch(void* const* d_in, const int* in_sizes, int n_in,
                              void* d_out, int out_size, void* d_ws, size_t ws_size,
                              hipStream_t stream) {
    const float* pred = (const float*)d_in[0];
    const int*   tgt  = (const int*)d_in[1];
    float* out = (float*)d_out;
    float* ws  = (float*)d_ws;

    init_kernel<<<dim3((WS_TOTAL + 255) / 256), dim3(256), 0, stream>>>(ws, out);
    sums_kernel<<<dim3(128, NB), dim3(256), 0, stream>>>(pred, tgt, ws);
    means_kernel<<<dim3(1), dim3(512), 0, stream>>>(ws);
    dist_kernel<<<dim3(256, NB), dim3(256), 0, stream>>>(pred, tgt, ws, out);
}